// Round 2
// baseline (1983.851 us; speedup 1.0000x reference)
//
#include <hip/hip_runtime.h>
#include <hip/hip_bf16.h>

#define NROWS 8192

template<int MODE> __device__ __forceinline__ float actf(float v) {
    if constexpr (MODE == 1) return fmaxf(v, 0.f);
    else if constexpr (MODE == 2) return v > 0.f ? v : 0.2f * v;
    else return v;
}

// ---------------------------------------------------------------------------
// Fold all activation-free weight chains on device (one block, ~6 us):
//   WA = W1@Wg1@Wm1 [128,64],  bA = b1@Wg1@Wm1,  cA = bg1@Wm1 + bm1
//   WB = W2@Wg2@W3  [64,16],   bB = b2@Wg2@W3,   cB = bg2@W3  + b3
// Shapes: W1[128,128] Wg1[128,128] Wm1[128,64] W2[64,32] Wg2[32,32] W3[32,16]
// ---------------------------------------------------------------------------
__global__ __launch_bounds__(256) void fold_all(
    const float* __restrict__ W1, const float* __restrict__ b1,
    const float* __restrict__ Wg1, const float* __restrict__ bg1,
    const float* __restrict__ Wm1, const float* __restrict__ bm1,
    const float* __restrict__ W2, const float* __restrict__ b2,
    const float* __restrict__ Wg2, const float* __restrict__ bg2,
    const float* __restrict__ W3, const float* __restrict__ b3,
    float* __restrict__ ws) {
    float* WA = ws + 0;       // [128][64]
    float* bA = ws + 8192;    // [64]
    float* cA = ws + 8256;    // [64]
    float* WB = ws + 8320;    // [64][16]
    float* bB = ws + 9344;    // [16]
    float* cB = ws + 9360;    // [16]
    float* T2 = ws + 9376;    // [64][32]
    float* v1 = ws + 11424;   // [128]
    float* v2 = ws + 11552;   // [32]
    float* T1 = ws + 16384;   // [128][128]
    const int tid = threadIdx.x;

    // T1 = W1 @ Wg1  (128x128 @ 128x128)
    for (int o4 = tid; o4 < 128 * 32; o4 += 256) {
        int i = o4 >> 5, j4 = (o4 & 31) << 2;
        float4 acc = {0, 0, 0, 0};
        for (int k = 0; k < 128; ++k) {
            float a = W1[i * 128 + k];
            float4 g = *(const float4*)&Wg1[k * 128 + j4];
            acc.x += a * g.x; acc.y += a * g.y; acc.z += a * g.z; acc.w += a * g.w;
        }
        *(float4*)&T1[i * 128 + j4] = acc;
    }
    // v1 = b1 @ Wg1
    for (int j = tid; j < 128; j += 256) {
        float s = 0;
        for (int k = 0; k < 128; ++k) s += b1[k] * Wg1[k * 128 + j];
        v1[j] = s;
    }
    // T2 = W2 @ Wg2  ([64,32] @ [32,32] -> [64,32])
    for (int o4 = tid; o4 < 64 * 8; o4 += 256) {
        int i = o4 >> 3, j4 = (o4 & 7) << 2;
        float4 acc = {0, 0, 0, 0};
        for (int k = 0; k < 32; ++k) {
            float a = W2[i * 32 + k];
            float4 g = *(const float4*)&Wg2[k * 32 + j4];
            acc.x += a * g.x; acc.y += a * g.y; acc.z += a * g.z; acc.w += a * g.w;
        }
        *(float4*)&T2[i * 32 + j4] = acc;
    }
    // v2 = b2 @ Wg2  (b2 is [32])
    for (int j = tid; j < 32; j += 256) {
        float s = 0;
        for (int k = 0; k < 32; ++k) s += b2[k] * Wg2[k * 32 + j];
        v2[j] = s;
    }
    __syncthreads();
    // WA = T1 @ Wm1  (128x128 @ 128x64)
    for (int o4 = tid; o4 < 128 * 16; o4 += 256) {
        int i = o4 >> 4, j4 = (o4 & 15) << 2;
        float4 acc = {0, 0, 0, 0};
        for (int k = 0; k < 128; ++k) {
            float a = T1[i * 128 + k];
            float4 g = *(const float4*)&Wm1[k * 64 + j4];
            acc.x += a * g.x; acc.y += a * g.y; acc.z += a * g.z; acc.w += a * g.w;
        }
        *(float4*)&WA[i * 64 + j4] = acc;
    }
    // bA = v1 @ Wm1 ; cA = bg1 @ Wm1 + bm1
    for (int j = tid; j < 64; j += 256) {
        float s = 0, c = 0;
        for (int k = 0; k < 128; ++k) {
            s += v1[k] * Wm1[k * 64 + j];
            c += bg1[k] * Wm1[k * 64 + j];
        }
        bA[j] = s; cA[j] = c + bm1[j];
    }
    // WB = T2 @ W3  ([64,32] @ [32,16])
    for (int o4 = tid; o4 < 64 * 4; o4 += 256) {
        int i = o4 >> 2, j4 = (o4 & 3) << 2;
        float4 acc = {0, 0, 0, 0};
        for (int k = 0; k < 32; ++k) {
            float a = T2[i * 32 + k];
            float4 g = *(const float4*)&W3[k * 16 + j4];
            acc.x += a * g.x; acc.y += a * g.y; acc.z += a * g.z; acc.w += a * g.w;
        }
        *(float4*)&WB[i * 16 + j4] = acc;
    }
    // bB = v2 @ W3 ; cB = bg2 @ W3 + b3
    for (int j = tid; j < 16; j += 256) {
        float s = 0, c = 0;
        for (int k = 0; k < 32; ++k) {
            s += v2[k] * W3[k * 16 + j];
            c += bg2[k] * W3[k * 16 + j];
        }
        bB[j] = s; cB[j] = c + b3[j];
    }
}

// ---------------------------------------------------------------------------
// Small row GEMM: out[N,M] = AOUT( AIN(in)[N,K] @ W[K,M] + bias )
// 32 rows/block, W + transposed input tile staged in LDS.
// ---------------------------------------------------------------------------
template<int K, int M, int AIN, int AOUT>
__global__ __launch_bounds__(256) void gemm_rows(
    const float* __restrict__ in, const float* __restrict__ W,
    const float* __restrict__ bias, float* __restrict__ out) {
    constexpr int RB = 32;
    constexpr int TNs = (M >= 64) ? 4 : 2;
    constexpr int TXs = M / TNs;
    constexpr int TYs = 256 / TXs;
    constexpr int TMs = RB / TYs;
    static_assert(TMs >= 1 && TMs * TYs == RB, "bad cfg");
    __shared__ float in_t[K][RB + 4];
    __shared__ float w_s[K * M];
    __shared__ float bias_s[M];
    const int tid = threadIdx.x;
    const int b0 = blockIdx.x * RB;
    constexpr int K4 = K / 4;
    for (int g = tid; g < RB * K4; g += 256) {
        int r = g / K4, c4 = g % K4;
        float4 v = *(const float4*)&in[(size_t)(b0 + r) * K + c4 * 4];
        v.x = actf<AIN>(v.x); v.y = actf<AIN>(v.y);
        v.z = actf<AIN>(v.z); v.w = actf<AIN>(v.w);
        in_t[c4 * 4 + 0][r] = v.x;
        in_t[c4 * 4 + 1][r] = v.y;
        in_t[c4 * 4 + 2][r] = v.z;
        in_t[c4 * 4 + 3][r] = v.w;
    }
    for (int g = tid; g < K * M / 4; g += 256)
        ((float4*)w_s)[g] = ((const float4*)W)[g];
    if (tid < M) bias_s[tid] = bias ? bias[tid] : 0.f;
    __syncthreads();

    const int tx = tid % TXs, ty = tid / TXs;
    const int c0 = tx * TNs, r0 = ty * TMs;
    float acc[TMs][TNs] = {};
    for (int k = 0; k < K; ++k) {
        float a[TMs];
#pragma unroll
        for (int m = 0; m < TMs; ++m) a[m] = in_t[k][r0 + m];
        float w[TNs];
#pragma unroll
        for (int n = 0; n < TNs; ++n) w[n] = w_s[k * M + c0 + n];
#pragma unroll
        for (int m = 0; m < TMs; ++m)
#pragma unroll
            for (int n = 0; n < TNs; ++n) acc[m][n] += a[m] * w[n];
    }
#pragma unroll
    for (int m = 0; m < TMs; ++m) {
        float vres[TNs];
#pragma unroll
        for (int n = 0; n < TNs; ++n) vres[n] = actf<AOUT>(acc[m][n] + bias_s[c0 + n]);
        float* op = &out[(size_t)(b0 + r0 + m) * M + c0];
        if constexpr (TNs == 4) {
            float4 o4 = {vres[0], vres[1], vres[2], vres[3]};
            *(float4*)op = o4;
        } else {
            float2 o2 = {vres[0], vres[1]};
            *(float2*)op = o2;
        }
    }
}

// ---------------------------------------------------------------------------
// Prefill g[i,c] = bias[c] (+ res[i,c])
// ---------------------------------------------------------------------------
template<int F>
__global__ __launch_bounds__(256) void prefill(
    float* __restrict__ g, const float* __restrict__ bias,
    const float* __restrict__ res) {
    int e4 = blockIdx.x * 256 + threadIdx.x;
    constexpr int TOT4 = NROWS * F / 4;
    if (e4 >= TOT4) return;
    int col4 = (e4 % (F / 4)) * 4;
    float4 b = *(const float4*)&bias[col4];
    if (res) {
        float4 r = ((const float4*)res)[e4];
        b.x += r.x; b.y += r.y; b.z += r.z; b.w += r.w;
    }
    ((float4*)g)[e4] = b;
}

// ---------------------------------------------------------------------------
// Big aggregation: C += (adj .* dis) @ S   (split-K, atomic accumulate)
// BM=256 rows/block, BK=32, adj*dis staged transposed in LDS,
// S columns read straight from L1/L2 (S is <=2MB, cache resident).
// ---------------------------------------------------------------------------
template<int F, int TX, int TM, int KS>
__global__ __launch_bounds__(256, 2) void bigpass(
    const float* __restrict__ adj, const float* __restrict__ dis,
    const float* __restrict__ S, float* __restrict__ C) {
    constexpr int TN = 16;
    constexpr int TY = 256 / TX;
    constexpr int BM = TY * TM;              // 256
    constexpr int BK = 32;
    constexpr int KCH = NROWS / KS;          // K chunk per split
    static_assert(BM == 256 && TX * TN == F, "cfg");
    __shared__ float w_lds[BK][BM + 4];
    const int tid = threadIdx.x;
    const int i0 = blockIdx.x * BM;
    const int k0base = blockIdx.y * KCH;
    const int tx = tid % TX;
    const int ty = tid / TX;
    float acc[TM][TN] = {};
    const float4* adj4 = (const float4*)adj;
    const float4* dis4 = (const float4*)dis;

    for (int t = 0; t < KCH / BK; ++t) {
        const int k0 = k0base + t * BK;
        // stage BM x BK tile of adj*dis, transposed into LDS
#pragma unroll
        for (int j = 0; j < (BM * BK) / (256 * 4); ++j) {   // 8 float4 per thread
            int g = j * 256 + tid;
            int r = g >> 3;          // 8 float4 per row (BK=32)
            int c4 = g & 7;
            int gi = (i0 + r) * (NROWS / 4) + (k0 >> 2) + c4;
            float4 av = adj4[gi];
            float4 dv = dis4[gi];
            int c = c4 * 4;
            w_lds[c + 0][r] = av.x * dv.x;
            w_lds[c + 1][r] = av.y * dv.y;
            w_lds[c + 2][r] = av.z * dv.z;
            w_lds[c + 3][r] = av.w * dv.w;
        }
        __syncthreads();
#pragma unroll 4
        for (int kk = 0; kk < BK; ++kk) {
            const float* srow = &S[(k0 + kk) * F + tx * TN];
            float4 sv[TN / 4];
#pragma unroll
            for (int n4 = 0; n4 < TN / 4; ++n4) sv[n4] = ((const float4*)srow)[n4];
            float a[TM];
            if constexpr (TM == 4) {
                float4 av = *(const float4*)&w_lds[kk][ty * 4];
                a[0] = av.x; a[1] = av.y; a[2] = av.z; a[3] = av.w;
            } else {
                a[0] = w_lds[kk][ty];
            }
#pragma unroll
            for (int m = 0; m < TM; ++m) {
#pragma unroll
                for (int n4 = 0; n4 < TN / 4; ++n4) {
                    acc[m][n4 * 4 + 0] += a[m] * sv[n4].x;
                    acc[m][n4 * 4 + 1] += a[m] * sv[n4].y;
                    acc[m][n4 * 4 + 2] += a[m] * sv[n4].z;
                    acc[m][n4 * 4 + 3] += a[m] * sv[n4].w;
                }
            }
        }
        __syncthreads();
    }
#pragma unroll
    for (int m = 0; m < TM; ++m) {
        float* crow = C + (size_t)(i0 + ty * TM + m) * F + tx * TN;
#pragma unroll
        for (int n = 0; n < TN; ++n) unsafeAtomicAdd(&crow[n], acc[m][n]);
    }
}

extern "C" void kernel_launch(void* const* d_in, const int* in_sizes, int n_in,
                              void* d_out, int out_size, void* d_ws, size_t ws_size,
                              hipStream_t stream) {
    const float* x   = (const float*)d_in[0];
    const float* adj = (const float*)d_in[1];
    const float* dis = (const float*)d_in[2];
    const float* W1  = (const float*)d_in[3];
    const float* b1  = (const float*)d_in[4];
    const float* Wg1 = (const float*)d_in[5];
    const float* bg1 = (const float*)d_in[6];
    const float* Wm1 = (const float*)d_in[7];
    const float* bm1 = (const float*)d_in[8];
    const float* Wm2 = (const float*)d_in[9];
    const float* bm2 = (const float*)d_in[10];
    const float* Wm3 = (const float*)d_in[11];
    const float* bm3 = (const float*)d_in[12];
    const float* Wm4 = (const float*)d_in[13];
    const float* bm4 = (const float*)d_in[14];
    const float* Wgh = (const float*)d_in[15];
    const float* bgh = (const float*)d_in[16];
    const float* W2  = (const float*)d_in[17];
    const float* b2  = (const float*)d_in[18];
    const float* Wg2 = (const float*)d_in[19];
    const float* bg2 = (const float*)d_in[20];
    const float* W3  = (const float*)d_in[21];
    const float* b3  = (const float*)d_in[22];
    float* ws  = (float*)d_ws;
    float* out = (float*)d_out;

    float* WA = ws + 0;
    float* bA = ws + 8192;
    float* WB = ws + 8320;
    float* bB = ws + 9344;
    float* cA = ws + 8256;
    float* cB = ws + 9360;
    float* sA = ws + 65536;           // [8192,64]
    float* gA = sA + 8192 * 64;       // [8192,64]
    float* h2 = gA + 8192 * 64;       // [8192,128]
    float* h3 = h2 + 8192 * 128;      // [8192,64]
    float* h4 = h3 + 8192 * 64;       // [8192,64]
    float* s2 = h4 + 8192 * 64;       // [8192,64]
    float* g2 = s2 + 8192 * 64;       // [8192,64]
    float* sB = g2 + 8192 * 64;       // [8192,16]

    fold_all<<<1, 256, 0, stream>>>(W1, b1, Wg1, bg1, Wm1, bm1,
                                    W2, b2, Wg2, bg2, W3, b3, ws);
    // sA = x @ WA + bA
    gemm_rows<128, 64, 0, 0><<<256, 256, 0, stream>>>(x, WA, bA, sA);
    // gA = cA ; gA += A @ sA        (gA_raw; h1 = lrelu(gA) applied on next load)
    prefill<64><<<512, 256, 0, stream>>>(gA, cA, nullptr);
    bigpass<64, 4, 4, 16><<<dim3(32, 16), 256, 0, stream>>>(adj, dis, sA, gA);
    // h2 = lrelu(lrelu(gA) @ Wm2 + bm2)
    gemm_rows<64, 128, 2, 2><<<256, 256, 0, stream>>>(gA, Wm2, bm2, h2);
    // h3 = lrelu(h2 @ Wm3 + bm3)
    gemm_rows<128, 64, 0, 2><<<256, 256, 0, stream>>>(h2, Wm3, bm3, h3);
    // h4 = relu(h3 @ Wm4 + bm4)
    gemm_rows<64, 64, 0, 1><<<256, 256, 0, stream>>>(h3, Wm4, bm4, h4);
    // s2 = h4 @ Wgh
    gemm_rows<64, 64, 0, 0><<<256, 256, 0, stream>>>(h4, Wgh, nullptr, s2);
    // g2 = bgh + h4 ; g2 += A @ s2  (g2_raw; relu applied on next load)
    prefill<64><<<512, 256, 0, stream>>>(g2, bgh, h4);
    bigpass<64, 4, 4, 16><<<dim3(32, 16), 256, 0, stream>>>(adj, dis, s2, g2);
    // sB = relu(g2) @ WB + bB
    gemm_rows<64, 16, 1, 0><<<256, 256, 0, stream>>>(g2, WB, bB, sB);
    // out = cB ; out += A @ sB
    prefill<16><<<128, 256, 0, stream>>>(out, cB, nullptr);
    bigpass<16, 1, 1, 16><<<dim3(32, 16), 256, 0, stream>>>(adj, dis, sB, out);
}

// Round 3
// 504.702 us; speedup vs baseline: 3.9307x; 3.9307x over previous
//
#include <hip/hip_runtime.h>
#include <hip/hip_bf16.h>

#define NROWS 8192
typedef unsigned short u16;
typedef short bf16x8 __attribute__((ext_vector_type(8)));
typedef float f32x4 __attribute__((ext_vector_type(4)));

__device__ __forceinline__ u16 f2b(float f) {   // fp32 -> bf16 RNE (finite data)
    unsigned u = __float_as_uint(f);
    unsigned r = (u + 0x7fffu + ((u >> 16) & 1u)) >> 16;
    return (u16)r;
}

template<int MODE> __device__ __forceinline__ float actf(float v) {
    if constexpr (MODE == 1) return fmaxf(v, 0.f);
    else if constexpr (MODE == 2) return v > 0.f ? v : 0.2f * v;
    else return v;
}

// ---------------------------------------------------------------------------
// Fold activation-free weight chains:
//   WA = W1@Wg1@Wm1 [128,64], bA = b1@Wg1@Wm1, cA = bg1@Wm1 + bm1
//   WB = W2@Wg2@W3  [64,16],  bB = b2@Wg2@W3,  cB = bg2@W3  + b3
// Shapes: W1[128,128] Wg1[128,128] Wm1[128,64] W2[64,32] Wg2[32,32] W3[32,16]
// ---------------------------------------------------------------------------
__global__ __launch_bounds__(256) void fold_all(
    const float* __restrict__ W1, const float* __restrict__ b1,
    const float* __restrict__ Wg1, const float* __restrict__ bg1,
    const float* __restrict__ Wm1, const float* __restrict__ bm1,
    const float* __restrict__ W2, const float* __restrict__ b2,
    const float* __restrict__ Wg2, const float* __restrict__ bg2,
    const float* __restrict__ W3, const float* __restrict__ b3,
    float* __restrict__ ws) {
    float* WA = ws + 0;       // [128][64]
    float* bA = ws + 8192;    // [64]
    float* cA = ws + 8256;    // [64]
    float* WB = ws + 8320;    // [64][16]
    float* bB = ws + 9344;    // [16]
    float* cB = ws + 9360;    // [16]
    float* T2 = ws + 9376;    // [64][32]
    float* v1 = ws + 11424;   // [128]
    float* v2 = ws + 11552;   // [32]
    float* T1 = ws + 16384;   // [128][128]
    const int tid = threadIdx.x;

    for (int o4 = tid; o4 < 128 * 32; o4 += 256) {          // T1 = W1 @ Wg1
        int i = o4 >> 5, j4 = (o4 & 31) << 2;
        float4 acc = {0, 0, 0, 0};
        for (int k = 0; k < 128; ++k) {
            float a = W1[i * 128 + k];
            float4 g = *(const float4*)&Wg1[k * 128 + j4];
            acc.x += a * g.x; acc.y += a * g.y; acc.z += a * g.z; acc.w += a * g.w;
        }
        *(float4*)&T1[i * 128 + j4] = acc;
    }
    for (int j = tid; j < 128; j += 256) {                  // v1 = b1 @ Wg1
        float s = 0;
        for (int k = 0; k < 128; ++k) s += b1[k] * Wg1[k * 128 + j];
        v1[j] = s;
    }
    for (int o4 = tid; o4 < 64 * 8; o4 += 256) {            // T2 = W2 @ Wg2
        int i = o4 >> 3, j4 = (o4 & 7) << 2;
        float4 acc = {0, 0, 0, 0};
        for (int k = 0; k < 32; ++k) {
            float a = W2[i * 32 + k];
            float4 g = *(const float4*)&Wg2[k * 32 + j4];
            acc.x += a * g.x; acc.y += a * g.y; acc.z += a * g.z; acc.w += a * g.w;
        }
        *(float4*)&T2[i * 32 + j4] = acc;
    }
    for (int j = tid; j < 32; j += 256) {                   // v2 = b2 @ Wg2
        float s = 0;
        for (int k = 0; k < 32; ++k) s += b2[k] * Wg2[k * 32 + j];
        v2[j] = s;
    }
    __syncthreads();
    for (int o4 = tid; o4 < 128 * 16; o4 += 256) {          // WA = T1 @ Wm1
        int i = o4 >> 4, j4 = (o4 & 15) << 2;
        float4 acc = {0, 0, 0, 0};
        for (int k = 0; k < 128; ++k) {
            float a = T1[i * 128 + k];
            float4 g = *(const float4*)&Wm1[k * 64 + j4];
            acc.x += a * g.x; acc.y += a * g.y; acc.z += a * g.z; acc.w += a * g.w;
        }
        *(float4*)&WA[i * 64 + j4] = acc;
    }
    for (int j = tid; j < 64; j += 256) {                   // bA, cA
        float s = 0, c = 0;
        for (int k = 0; k < 128; ++k) {
            s += v1[k] * Wm1[k * 64 + j];
            c += bg1[k] * Wm1[k * 64 + j];
        }
        bA[j] = s; cA[j] = c + bm1[j];
    }
    for (int o4 = tid; o4 < 64 * 4; o4 += 256) {            // WB = T2 @ W3
        int i = o4 >> 2, j4 = (o4 & 3) << 2;
        float4 acc = {0, 0, 0, 0};
        for (int k = 0; k < 32; ++k) {
            float a = T2[i * 32 + k];
            float4 g = *(const float4*)&W3[k * 16 + j4];
            acc.x += a * g.x; acc.y += a * g.y; acc.z += a * g.z; acc.w += a * g.w;
        }
        *(float4*)&WB[i * 16 + j4] = acc;
    }
    for (int j = tid; j < 16; j += 256) {                   // bB, cB
        float s = 0, c = 0;
        for (int k = 0; k < 32; ++k) {
            s += v2[k] * W3[k * 16 + j];
            c += bg2[k] * W3[k * 16 + j];
        }
        bB[j] = s; cB[j] = c + b3[j];
    }
}

// ---------------------------------------------------------------------------
// Abf[i] = bf16(adj[i] * dis[i])   (streaming, 512MB R + 128MB W)
// ---------------------------------------------------------------------------
__global__ __launch_bounds__(256) void mul_bf16(
    const float4* __restrict__ adj, const float4* __restrict__ dis,
    u16* __restrict__ Ab) {
    const size_t tot = (size_t)NROWS * NROWS / 8;
    size_t i = (size_t)blockIdx.x * 256 + threadIdx.x;
    const size_t stride = (size_t)gridDim.x * 256;
    for (; i < tot; i += stride) {
        float4 a0 = adj[2 * i], a1 = adj[2 * i + 1];
        float4 d0 = dis[2 * i], d1 = dis[2 * i + 1];
        bf16x8 r;
        r[0] = (short)f2b(a0.x * d0.x); r[1] = (short)f2b(a0.y * d0.y);
        r[2] = (short)f2b(a0.z * d0.z); r[3] = (short)f2b(a0.w * d0.w);
        r[4] = (short)f2b(a1.x * d1.x); r[5] = (short)f2b(a1.y * d1.y);
        r[6] = (short)f2b(a1.z * d1.z); r[7] = (short)f2b(a1.w * d1.w);
        *(bf16x8*)(Ab + i * 8) = r;
    }
}

// ---------------------------------------------------------------------------
// Small row GEMM: out = AOUT( AIN(in)[N,K] @ W[K,M] + bias )
// OUTT=0: fp32 row-major [N,M].  OUTT=1: bf16 TRANSPOSED [M][NROWS] (S^T).
// ---------------------------------------------------------------------------
template<int K, int M, int AIN, int AOUT, int OUTT>
__global__ __launch_bounds__(256) void gemm_rows(
    const float* __restrict__ in, const float* __restrict__ W,
    const float* __restrict__ bias, void* __restrict__ outv) {
    constexpr int RB = 32;
    constexpr int TNs = (M >= 64) ? 4 : 2;
    constexpr int TXs = M / TNs;
    constexpr int TYs = 256 / TXs;
    constexpr int TMs = RB / TYs;
    static_assert(TMs >= 1 && TMs * TYs == RB, "bad cfg");
    __shared__ float in_t[K][RB + 4];
    __shared__ float w_s[K * M];
    __shared__ float bias_s[M];
    const int tid = threadIdx.x;
    const int b0 = blockIdx.x * RB;
    constexpr int K4 = K / 4;
    for (int g = tid; g < RB * K4; g += 256) {
        int r = g / K4, c4 = g % K4;
        float4 v = *(const float4*)&in[(size_t)(b0 + r) * K + c4 * 4];
        v.x = actf<AIN>(v.x); v.y = actf<AIN>(v.y);
        v.z = actf<AIN>(v.z); v.w = actf<AIN>(v.w);
        in_t[c4 * 4 + 0][r] = v.x;
        in_t[c4 * 4 + 1][r] = v.y;
        in_t[c4 * 4 + 2][r] = v.z;
        in_t[c4 * 4 + 3][r] = v.w;
    }
    for (int g = tid; g < K * M / 4; g += 256)
        ((float4*)w_s)[g] = ((const float4*)W)[g];
    if (tid < M) bias_s[tid] = bias ? bias[tid] : 0.f;
    __syncthreads();

    const int tx = tid % TXs, ty = tid / TXs;
    const int c0 = tx * TNs, r0 = ty * TMs;
    float acc[TMs][TNs] = {};
    for (int k = 0; k < K; ++k) {
        float a[TMs];
#pragma unroll
        for (int m = 0; m < TMs; ++m) a[m] = in_t[k][r0 + m];
        float w[TNs];
#pragma unroll
        for (int n = 0; n < TNs; ++n) w[n] = w_s[k * M + c0 + n];
#pragma unroll
        for (int m = 0; m < TMs; ++m)
#pragma unroll
            for (int n = 0; n < TNs; ++n) acc[m][n] += a[m] * w[n];
    }
#pragma unroll
    for (int m = 0; m < TMs; ++m) {
        float vres[TNs];
#pragma unroll
        for (int n = 0; n < TNs; ++n) vres[n] = actf<AOUT>(acc[m][n] + bias_s[c0 + n]);
        if constexpr (OUTT == 0) {
            float* op = &((float*)outv)[(size_t)(b0 + r0 + m) * M + c0];
            if constexpr (TNs == 4) { float4 o4 = {vres[0], vres[1], vres[2], vres[3]}; *(float4*)op = o4; }
            else                    { float2 o2 = {vres[0], vres[1]}; *(float2*)op = o2; }
        } else {
            u16* ot = (u16*)outv;
#pragma unroll
            for (int n = 0; n < TNs; ++n)
                ot[(size_t)(c0 + n) * NROWS + (b0 + r0 + m)] = f2b(vres[n]);
        }
    }
}

// ---------------------------------------------------------------------------
// MFMA aggregation: P[ky] = A[rows, kchunk] @ S   (bf16 MFMA, no LDS, no atomics)
// wave: 16 rows x F cols.  A-frag & B-frag = direct 16B global loads.
// St is S^T [F][NROWS] bf16 (L2-resident).  PRE: A from Abf; else from adj*dis.
// ---------------------------------------------------------------------------
template<int F, bool PRE>
__global__ __launch_bounds__(256) void agg_mfma(
    const u16* __restrict__ Abf, const float* __restrict__ adj,
    const float* __restrict__ dis, const u16* __restrict__ St,
    float* __restrict__ Pout) {
    constexpr int CT = F / 16;
    constexpr int KS = 4;
    constexpr int KCH = NROWS / KS;
    const int lane = threadIdx.x & 63;
    const int wid  = threadIdx.x >> 6;
    const int r0   = blockIdx.x * 64 + wid * 16;
    const int ky   = blockIdx.y;
    const int l15  = lane & 15;
    const int kb   = (lane >> 4) * 8;
    const int k0   = ky * KCH;
    f32x4 acc[CT] = {};
    size_t aoff = (size_t)(r0 + l15) * NROWS + k0 + kb;
    const u16* Bbase = St + (size_t)l15 * NROWS + k0 + kb;
#pragma unroll 4
    for (int ks = 0; ks < KCH; ks += 32) {
        bf16x8 af;
        if constexpr (PRE) {
            af = *(const bf16x8*)(Abf + aoff);
        } else {
            float4 a0 = *(const float4*)(adj + aoff);
            float4 a1 = *(const float4*)(adj + aoff + 4);
            float4 d0 = *(const float4*)(dis + aoff);
            float4 d1 = *(const float4*)(dis + aoff + 4);
            af[0] = (short)f2b(a0.x * d0.x); af[1] = (short)f2b(a0.y * d0.y);
            af[2] = (short)f2b(a0.z * d0.z); af[3] = (short)f2b(a0.w * d0.w);
            af[4] = (short)f2b(a1.x * d1.x); af[5] = (short)f2b(a1.y * d1.y);
            af[6] = (short)f2b(a1.z * d1.z); af[7] = (short)f2b(a1.w * d1.w);
        }
#pragma unroll
        for (int ct = 0; ct < CT; ++ct) {
            bf16x8 bf = *(const bf16x8*)(Bbase + (size_t)ct * 16 * NROWS + ks);
            acc[ct] = __builtin_amdgcn_mfma_f32_16x16x32_bf16(af, bf, acc[ct], 0, 0, 0);
        }
        aoff += 32;
    }
    // C/D layout: col = lane&15, row = (lane>>4)*4 + i   [m89-verified]
    float* P = Pout + (size_t)ky * ((size_t)NROWS * F);
    const int rb = r0 + (lane >> 4) * 4;
#pragma unroll
    for (int ct = 0; ct < CT; ++ct)
#pragma unroll
        for (int i = 0; i < 4; ++i)
            P[(size_t)(rb + i) * F + ct * 16 + l15] = acc[ct][i];
}

// ---------------------------------------------------------------------------
// out = sum_{ky} P[ky] + bias[col] (+ res)
// ---------------------------------------------------------------------------
template<int F>
__global__ __launch_bounds__(256) void reduce_add(
    const float* __restrict__ P, const float* __restrict__ bias,
    const float* __restrict__ res, float* __restrict__ out) {
    constexpr int TOT4 = NROWS * F / 4;
    int i = blockIdx.x * 256 + threadIdx.x;
    if (i >= TOT4) return;
    constexpr size_t STR = (size_t)NROWS * F / 4;
    const float4* P4 = (const float4*)P;
    float4 s = P4[i];
    float4 t1 = P4[i + STR], t2 = P4[i + 2 * STR], t3 = P4[i + 3 * STR];
    s.x += t1.x + t2.x + t3.x; s.y += t1.y + t2.y + t3.y;
    s.z += t1.z + t2.z + t3.z; s.w += t1.w + t2.w + t3.w;
    float4 b = *(const float4*)&bias[(i % (F / 4)) * 4];
    s.x += b.x; s.y += b.y; s.z += b.z; s.w += b.w;
    if (res) {
        float4 r = ((const float4*)res)[i];
        s.x += r.x; s.y += r.y; s.z += r.z; s.w += r.w;
    }
    ((float4*)out)[i] = s;
}

extern "C" void kernel_launch(void* const* d_in, const int* in_sizes, int n_in,
                              void* d_out, int out_size, void* d_ws, size_t ws_size,
                              hipStream_t stream) {
    const float* x   = (const float*)d_in[0];
    const float* adj = (const float*)d_in[1];
    const float* dis = (const float*)d_in[2];
    const float* W1  = (const float*)d_in[3];
    const float* b1  = (const float*)d_in[4];
    const float* Wg1 = (const float*)d_in[5];
    const float* bg1 = (const float*)d_in[6];
    const float* Wm1 = (const float*)d_in[7];
    const float* bm1 = (const float*)d_in[8];
    const float* Wm2 = (const float*)d_in[9];
    const float* bm2 = (const float*)d_in[10];
    const float* Wm3 = (const float*)d_in[11];
    const float* bm3 = (const float*)d_in[12];
    const float* Wm4 = (const float*)d_in[13];
    const float* bm4 = (const float*)d_in[14];
    const float* Wgh = (const float*)d_in[15];
    const float* bgh = (const float*)d_in[16];
    const float* W2  = (const float*)d_in[17];
    const float* b2  = (const float*)d_in[18];
    const float* Wg2 = (const float*)d_in[19];
    const float* bg2 = (const float*)d_in[20];
    const float* W3  = (const float*)d_in[21];
    const float* b3  = (const float*)d_in[22];
    float* ws  = (float*)d_ws;
    float* out = (float*)d_out;

    const size_t ABF_FLOATS = (size_t)NROWS * NROWS / 2;   // 128MB as floats
    const size_t NEED_PRE_BYTES = (ABF_FLOATS + 5873664ULL) * 4ULL;  // ~150.4MB
    const bool pre = ws_size >= NEED_PRE_BYTES;

    float* base = ws + (pre ? ABF_FLOATS : 0);
    float* wsW  = base;                       // fold area: 40960 floats
    float* StA_f = wsW + 40960;               // S^T bf16 [64][8192] = 262144 floats
    float* St2_f = StA_f + 262144;
    float* StB_f = St2_f + 262144;            // [16][8192] bf16 = 65536 floats
    float* P     = StB_f + 65536;             // partials: 4*8192*64 = 2097152 floats
    float* gA    = P + 2097152;               // [8192,64]
    float* h2    = gA + 524288;               // [8192,128]
    float* h3    = h2 + 1048576;              // [8192,64]
    float* h4    = h3 + 524288;               // [8192,64]
    float* g2    = h4 + 524288;               // [8192,64]

    u16* Abf = (u16*)ws;
    u16* StA = (u16*)StA_f;
    u16* St2 = (u16*)St2_f;
    u16* StB = (u16*)StB_f;
    const float* WA = wsW + 0;
    const float* bA = wsW + 8192;
    const float* cA = wsW + 8256;
    const float* WB = wsW + 8320;
    const float* bB = wsW + 9344;
    const float* cB = wsW + 9360;

    fold_all<<<1, 256, 0, stream>>>(W1, b1, Wg1, bg1, Wm1, bm1,
                                    W2, b2, Wg2, bg2, W3, b3, wsW);
    if (pre)
        mul_bf16<<<4096, 256, 0, stream>>>((const float4*)adj, (const float4*)dis, Abf);

    // pass 1: sA^T = (x @ WA + bA)^T ; gA = A@sA + cA
    gemm_rows<128, 64, 0, 0, 1><<<256, 256, 0, stream>>>(x, WA, bA, StA);
    if (pre) agg_mfma<64, true ><<<dim3(128, 4), 256, 0, stream>>>(Abf, nullptr, nullptr, StA, P);
    else     agg_mfma<64, false><<<dim3(128, 4), 256, 0, stream>>>(nullptr, adj, dis, StA, P);
    reduce_add<64><<<512, 256, 0, stream>>>(P, cA, nullptr, gA);

    // med chain
    gemm_rows<64, 128, 2, 2, 0><<<256, 256, 0, stream>>>(gA, Wm2, bm2, h2);
    gemm_rows<128, 64, 0, 2, 0><<<256, 256, 0, stream>>>(h2, Wm3, bm3, h3);
    gemm_rows<64, 64, 0, 1, 0><<<256, 256, 0, stream>>>(h3, Wm4, bm4, h4);

    // pass 2: s2^T = (h4 @ Wgh)^T ; g2 = A@s2 + bgh + h4
    gemm_rows<64, 64, 0, 0, 1><<<256, 256, 0, stream>>>(h4, Wgh, nullptr, St2);
    if (pre) agg_mfma<64, true ><<<dim3(128, 4), 256, 0, stream>>>(Abf, nullptr, nullptr, St2, P);
    else     agg_mfma<64, false><<<dim3(128, 4), 256, 0, stream>>>(nullptr, adj, dis, St2, P);
    reduce_add<64><<<512, 256, 0, stream>>>(P, bgh, h4, g2);

    // pass 3: sB^T = (relu(g2) @ WB + bB)^T ; out = A@sB + cB
    gemm_rows<64, 16, 1, 0, 1><<<256, 256, 0, stream>>>(g2, WB, bB, StB);
    if (pre) agg_mfma<16, true ><<<dim3(128, 4), 256, 0, stream>>>(Abf, nullptr, nullptr, StB, P);
    else     agg_mfma<16, false><<<dim3(128, 4), 256, 0, stream>>>(nullptr, adj, dis, StB, P);
    reduce_add<16><<<128, 256, 0, stream>>>(P, cB, nullptr, out);
}

// Round 4
// 383.709 us; speedup vs baseline: 5.1702x; 1.3153x over previous
//
#include <hip/hip_runtime.h>
#include <hip/hip_bf16.h>

#define NROWS 8192
typedef unsigned short u16;
typedef short bf16x8 __attribute__((ext_vector_type(8)));
typedef float f32x4 __attribute__((ext_vector_type(4)));

__device__ __forceinline__ u16 f2b(float f) {   // fp32 -> bf16 RNE (finite data)
    unsigned u = __float_as_uint(f);
    unsigned r = (u + 0x7fffu + ((u >> 16) & 1u)) >> 16;
    return (u16)r;
}

template<int MODE> __device__ __forceinline__ float actf(float v) {
    if constexpr (MODE == 1) return fmaxf(v, 0.f);
    else if constexpr (MODE == 2) return v > 0.f ? v : 0.2f * v;
    else return v;
}

// ---------------------------------------------------------------------------
// Weight folds, parallelized. ws layout (floats):
//   WA[128*64]@0  bA[64]@8192  cA[64]@8256  WB[64*16]@8320  bB[16]@9344
//   cB[16]@9360  T2[64*32]@9376  v1[128]@11424  v2[32]@11552  T1[128*128]@16384
// Shapes: W1[128,128] Wg1[128,128] Wm1[128,64] W2[64,32] Wg2[32,32] W3[32,16]
// ---------------------------------------------------------------------------
__global__ __launch_bounds__(256) void fold1(
    const float* __restrict__ W1, const float* __restrict__ b1,
    const float* __restrict__ Wg1,
    const float* __restrict__ W2, const float* __restrict__ b2,
    const float* __restrict__ Wg2, float* __restrict__ ws) {
    float* T2 = ws + 9376;
    float* v1 = ws + 11424;
    float* v2 = ws + 11552;
    float* T1 = ws + 16384;
    const int tid = threadIdx.x, b = blockIdx.x;
    if (b < 16) {                       // T1 = W1 @ Wg1 : rows [b*8, b*8+8)
        int i = b * 8 + (tid >> 5), j4 = (tid & 31) << 2;
        float4 acc = {0, 0, 0, 0};
        for (int k = 0; k < 128; ++k) {
            float a = W1[i * 128 + k];
            float4 g = *(const float4*)&Wg1[k * 128 + j4];
            acc.x += a * g.x; acc.y += a * g.y; acc.z += a * g.z; acc.w += a * g.w;
        }
        *(float4*)&T1[i * 128 + j4] = acc;
    } else if (b == 16) {               // v1 = b1 @ Wg1 ; v2 = b2 @ Wg2
        if (tid < 128) {
            float s = 0;
            for (int k = 0; k < 128; ++k) s += b1[k] * Wg1[k * 128 + tid];
            v1[tid] = s;
        } else if (tid < 160) {
            int j = tid - 128;
            float s = 0;
            for (int k = 0; k < 32; ++k) s += b2[k] * Wg2[k * 32 + j];
            v2[j] = s;
        }
    } else {                            // T2 = W2 @ Wg2  (512 float4 outs)
        for (int o4 = tid; o4 < 64 * 8; o4 += 256) {
            int i = o4 >> 3, j4 = (o4 & 7) << 2;
            float4 acc = {0, 0, 0, 0};
            for (int k = 0; k < 32; ++k) {
                float a = W2[i * 32 + k];
                float4 g = *(const float4*)&Wg2[k * 32 + j4];
                acc.x += a * g.x; acc.y += a * g.y; acc.z += a * g.z; acc.w += a * g.w;
            }
            *(float4*)&T2[i * 32 + j4] = acc;
        }
    }
}

__global__ __launch_bounds__(256) void fold2(
    const float* __restrict__ Wm1, const float* __restrict__ bm1,
    const float* __restrict__ bg1,
    const float* __restrict__ W3, const float* __restrict__ b3,
    const float* __restrict__ bg2, float* __restrict__ ws) {
    float* WA = ws + 0;
    float* bA = ws + 8192;
    float* cA = ws + 8256;
    float* WB = ws + 8320;
    float* bB = ws + 9344;
    float* cB = ws + 9360;
    const float* T2 = ws + 9376;
    const float* v1 = ws + 11424;
    const float* v2 = ws + 11552;
    const float* T1 = ws + 16384;
    const int tid = threadIdx.x, b = blockIdx.x;
    if (b < 8) {                        // WA = T1 @ Wm1 : rows [b*16, b*16+16)
        int i = b * 16 + (tid >> 4), j4 = (tid & 15) << 2;
        float4 acc = {0, 0, 0, 0};
        for (int k = 0; k < 128; ++k) {
            float a = T1[i * 128 + k];
            float4 g = *(const float4*)&Wm1[k * 64 + j4];
            acc.x += a * g.x; acc.y += a * g.y; acc.z += a * g.z; acc.w += a * g.w;
        }
        *(float4*)&WA[i * 64 + j4] = acc;
    } else if (b == 8) {                // bA,cA,bB,cB
        if (tid < 64) {
            float s = 0, c = 0;
            for (int k = 0; k < 128; ++k) {
                s += v1[k] * Wm1[k * 64 + tid];
                c += bg1[k] * Wm1[k * 64 + tid];
            }
            bA[tid] = s; cA[tid] = c + bm1[tid];
        } else if (tid < 80) {
            int j = tid - 64;
            float s = 0, c = 0;
            for (int k = 0; k < 32; ++k) {
                s += v2[k] * W3[k * 16 + j];
                c += bg2[k] * W3[k * 16 + j];
            }
            bB[j] = s; cB[j] = c + b3[j];
        }
    } else {                            // WB = T2 @ W3  (256 float4 outs)
        int i = tid >> 2, j4 = (tid & 3) << 2;
        float4 acc = {0, 0, 0, 0};
        for (int k = 0; k < 32; ++k) {
            float a = T2[i * 32 + k];
            float4 g = *(const float4*)&W3[k * 16 + j4];
            acc.x += a * g.x; acc.y += a * g.y; acc.z += a * g.z; acc.w += a * g.w;
        }
        *(float4*)&WB[i * 16 + j4] = acc;
    }
}

// ---------------------------------------------------------------------------
// Small row GEMM: out = AOUT( AIN(in)[N,K] @ W[K,M] + bias )
// OUTT=0: fp32 row-major [N,M].  OUTT=1: bf16 TRANSPOSED [M][NROWS] (S^T).
// ---------------------------------------------------------------------------
template<int K, int M, int AIN, int AOUT, int OUTT>
__global__ __launch_bounds__(256) void gemm_rows(
    const float* __restrict__ in, const float* __restrict__ W,
    const float* __restrict__ bias, void* __restrict__ outv) {
    constexpr int RB = 32;
    constexpr int TNs = (M >= 64) ? 4 : 2;
    constexpr int TXs = M / TNs;
    constexpr int TYs = 256 / TXs;
    constexpr int TMs = RB / TYs;
    static_assert(TMs >= 1 && TMs * TYs == RB, "bad cfg");
    __shared__ float in_t[K][RB + 4];
    __shared__ float w_s[K * M];
    __shared__ float bias_s[M];
    const int tid = threadIdx.x;
    const int b0 = blockIdx.x * RB;
    constexpr int K4 = K / 4;
    for (int g = tid; g < RB * K4; g += 256) {
        int r = g / K4, c4 = g % K4;
        float4 v = *(const float4*)&in[(size_t)(b0 + r) * K + c4 * 4];
        v.x = actf<AIN>(v.x); v.y = actf<AIN>(v.y);
        v.z = actf<AIN>(v.z); v.w = actf<AIN>(v.w);
        in_t[c4 * 4 + 0][r] = v.x;
        in_t[c4 * 4 + 1][r] = v.y;
        in_t[c4 * 4 + 2][r] = v.z;
        in_t[c4 * 4 + 3][r] = v.w;
    }
    for (int g = tid; g < K * M / 4; g += 256)
        ((float4*)w_s)[g] = ((const float4*)W)[g];
    if (tid < M) bias_s[tid] = bias ? bias[tid] : 0.f;
    __syncthreads();

    const int tx = tid % TXs, ty = tid / TXs;
    const int c0 = tx * TNs, r0 = ty * TMs;
    float acc[TMs][TNs] = {};
    for (int k = 0; k < K; ++k) {
        float a[TMs];
#pragma unroll
        for (int m = 0; m < TMs; ++m) a[m] = in_t[k][r0 + m];
        float w[TNs];
#pragma unroll
        for (int n = 0; n < TNs; ++n) w[n] = w_s[k * M + c0 + n];
#pragma unroll
        for (int m = 0; m < TMs; ++m)
#pragma unroll
            for (int n = 0; n < TNs; ++n) acc[m][n] += a[m] * w[n];
    }
#pragma unroll
    for (int m = 0; m < TMs; ++m) {
        float vres[TNs];
#pragma unroll
        for (int n = 0; n < TNs; ++n) vres[n] = actf<AOUT>(acc[m][n] + bias_s[c0 + n]);
        if constexpr (OUTT == 0) {
            float* op = &((float*)outv)[(size_t)(b0 + r0 + m) * M + c0];
            if constexpr (TNs == 4) { float4 o4 = {vres[0], vres[1], vres[2], vres[3]}; *(float4*)op = o4; }
            else                    { float2 o2 = {vres[0], vres[1]}; *(float2*)op = o2; }
        } else {
            u16* ot = (u16*)outv;
#pragma unroll
            for (int n = 0; n < TNs; ++n)
                ot[(size_t)(c0 + n) * NROWS + (b0 + r0 + m)] = f2b(vres[n]);
        }
    }
}

// ---------------------------------------------------------------------------
// MFMA aggregation: P[ky] = A[rows, kchunk] @ S   (bf16 MFMA, no LDS, no atomics)
// wave: 16 rows x F cols; A-frag/B-frag = direct 16B global loads.
// MODE 0: A from Abf (L3-warm).  MODE 1: A = bf16(adj*dis) on the fly
// (nontemporal reads), ALSO writes Abf (fused converter).  MODE 2: on the fly,
// no write (low-workspace fallback).
// ---------------------------------------------------------------------------
template<int F, int MODE>
__global__ __launch_bounds__(256) void agg_mfma(
    u16* __restrict__ Abf, const float* __restrict__ adj,
    const float* __restrict__ dis, const u16* __restrict__ St,
    float* __restrict__ Pout) {
    constexpr int CT = F / 16;
    constexpr int KS = 4;
    constexpr int KCH = NROWS / KS;
    const int lane = threadIdx.x & 63;
    const int wid  = threadIdx.x >> 6;
    const int r0   = blockIdx.x * 64 + wid * 16;
    const int ky   = blockIdx.y;
    const int l15  = lane & 15;
    const int kb   = (lane >> 4) * 8;
    const int k0   = ky * KCH;
    f32x4 acc[CT] = {};
    size_t aoff = (size_t)(r0 + l15) * NROWS + k0 + kb;
    const u16* Bbase = St + (size_t)l15 * NROWS + k0 + kb;
#pragma unroll 4
    for (int ks = 0; ks < KCH; ks += 32) {
        bf16x8 af;
        if constexpr (MODE == 0) {
            af = *(const bf16x8*)(Abf + aoff);
        } else {
            const f32x4* a4 = (const f32x4*)(adj + aoff);
            const f32x4* d4 = (const f32x4*)(dis + aoff);
            f32x4 a0 = __builtin_nontemporal_load(a4);
            f32x4 a1 = __builtin_nontemporal_load(a4 + 1);
            f32x4 d0 = __builtin_nontemporal_load(d4);
            f32x4 d1 = __builtin_nontemporal_load(d4 + 1);
#pragma unroll
            for (int j = 0; j < 4; ++j) {
                af[j]     = (short)f2b(a0[j] * d0[j]);
                af[j + 4] = (short)f2b(a1[j] * d1[j]);
            }
            if constexpr (MODE == 1)
                *(bf16x8*)(Abf + aoff) = af;   // normal store -> lands in L2/L3
        }
#pragma unroll
        for (int ct = 0; ct < CT; ++ct) {
            bf16x8 bf = *(const bf16x8*)(Bbase + (size_t)ct * 16 * NROWS + ks);
            acc[ct] = __builtin_amdgcn_mfma_f32_16x16x32_bf16(af, bf, acc[ct], 0, 0, 0);
        }
        aoff += 32;
    }
    // C/D layout: col = lane&15, row = (lane>>4)*4 + i   [m89-verified]
    float* P = Pout + (size_t)ky * ((size_t)NROWS * F);
    const int rb = r0 + (lane >> 4) * 4;
#pragma unroll
    for (int ct = 0; ct < CT; ++ct)
#pragma unroll
        for (int i = 0; i < 4; ++i)
            P[(size_t)(rb + i) * F + ct * 16 + l15] = acc[ct][i];
}

// ---------------------------------------------------------------------------
// out = sum_{ky} P[ky] + bias[col] (+ res)
// ---------------------------------------------------------------------------
template<int F>
__global__ __launch_bounds__(256) void reduce_add(
    const float* __restrict__ P, const float* __restrict__ bias,
    const float* __restrict__ res, float* __restrict__ out) {
    constexpr int TOT4 = NROWS * F / 4;
    int i = blockIdx.x * 256 + threadIdx.x;
    if (i >= TOT4) return;
    constexpr size_t STR = (size_t)NROWS * F / 4;
    const float4* P4 = (const float4*)P;
    float4 s = P4[i];
    float4 t1 = P4[i + STR], t2 = P4[i + 2 * STR], t3 = P4[i + 3 * STR];
    s.x += t1.x + t2.x + t3.x; s.y += t1.y + t2.y + t3.y;
    s.z += t1.z + t2.z + t3.z; s.w += t1.w + t2.w + t3.w;
    float4 b = *(const float4*)&bias[(i % (F / 4)) * 4];
    s.x += b.x; s.y += b.y; s.z += b.z; s.w += b.w;
    if (res) {
        float4 r = ((const float4*)res)[i];
        s.x += r.x; s.y += r.y; s.z += r.z; s.w += r.w;
    }
    ((float4*)out)[i] = s;
}

extern "C" void kernel_launch(void* const* d_in, const int* in_sizes, int n_in,
                              void* d_out, int out_size, void* d_ws, size_t ws_size,
                              hipStream_t stream) {
    const float* x   = (const float*)d_in[0];
    const float* adj = (const float*)d_in[1];
    const float* dis = (const float*)d_in[2];
    const float* W1  = (const float*)d_in[3];
    const float* b1  = (const float*)d_in[4];
    const float* Wg1 = (const float*)d_in[5];
    const float* bg1 = (const float*)d_in[6];
    const float* Wm1 = (const float*)d_in[7];
    const float* bm1 = (const float*)d_in[8];
    const float* Wm2 = (const float*)d_in[9];
    const float* bm2 = (const float*)d_in[10];
    const float* Wm3 = (const float*)d_in[11];
    const float* bm3 = (const float*)d_in[12];
    const float* Wm4 = (const float*)d_in[13];
    const float* bm4 = (const float*)d_in[14];
    const float* Wgh = (const float*)d_in[15];
    const float* bgh = (const float*)d_in[16];
    const float* W2  = (const float*)d_in[17];
    const float* b2  = (const float*)d_in[18];
    const float* Wg2 = (const float*)d_in[19];
    const float* bg2 = (const float*)d_in[20];
    const float* W3  = (const float*)d_in[21];
    const float* b3  = (const float*)d_in[22];
    float* ws  = (float*)d_ws;
    float* out = (float*)d_out;

    const size_t ABF_FLOATS = (size_t)NROWS * NROWS / 2;   // 128MB as floats
    const size_t NEED_PRE_BYTES = (ABF_FLOATS + 5873664ULL) * 4ULL;  // ~150.4MB
    const bool pre = ws_size >= NEED_PRE_BYTES;

    float* base = ws + (pre ? ABF_FLOATS : 0);
    float* wsW  = base;                       // fold area: 40960 floats
    float* StA_f = wsW + 40960;               // S^T bf16 [64][8192]
    float* St2_f = StA_f + 262144;
    float* StB_f = St2_f + 262144;            // [16][8192] bf16
    float* P     = StB_f + 65536;             // partials: 4*8192*64
    float* gA    = P + 2097152;               // [8192,64]
    float* h2    = gA + 524288;               // [8192,128]
    float* h3    = h2 + 1048576;              // [8192,64]
    float* h4    = h3 + 524288;               // [8192,64]
    float* g2    = h4 + 524288;               // [8192,64]

    u16* Abf = (u16*)ws;
    u16* StA = (u16*)StA_f;
    u16* St2 = (u16*)St2_f;
    u16* StB = (u16*)StB_f;
    const float* WA = wsW + 0;
    const float* bA = wsW + 8192;
    const float* cA = wsW + 8256;
    const float* WB = wsW + 8320;
    const float* bB = wsW + 9344;
    const float* cB = wsW + 9360;

    fold1<<<18, 256, 0, stream>>>(W1, b1, Wg1, W2, b2, Wg2, wsW);
    fold2<<<10, 256, 0, stream>>>(Wm1, bm1, bg1, W3, b3, bg2, wsW);

    // pass 1 (fused converter): sA^T = (x @ WA + bA)^T ; gA = A@sA + cA
    gemm_rows<128, 64, 0, 0, 1><<<256, 256, 0, stream>>>(x, WA, bA, StA);
    if (pre) agg_mfma<64, 1><<<dim3(128, 4), 256, 0, stream>>>(Abf, adj, dis, StA, P);
    else     agg_mfma<64, 2><<<dim3(128, 4), 256, 0, stream>>>(nullptr, adj, dis, StA, P);
    reduce_add<64><<<512, 256, 0, stream>>>(P, cA, nullptr, gA);

    // med chain
    gemm_rows<64, 128, 2, 2, 0><<<256, 256, 0, stream>>>(gA, Wm2, bm2, h2);
    gemm_rows<128, 64, 0, 2, 0><<<256, 256, 0, stream>>>(h2, Wm3, bm3, h3);
    gemm_rows<64, 64, 0, 1, 0><<<256, 256, 0, stream>>>(h3, Wm4, bm4, h4);

    // pass 2: s2^T = (h4 @ Wgh)^T ; g2 = A@s2 + bgh + h4
    gemm_rows<64, 64, 0, 0, 1><<<256, 256, 0, stream>>>(h4, Wgh, nullptr, St2);
    if (pre) agg_mfma<64, 0><<<dim3(128, 4), 256, 0, stream>>>(Abf, nullptr, nullptr, St2, P);
    else     agg_mfma<64, 2><<<dim3(128, 4), 256, 0, stream>>>(nullptr, adj, dis, St2, P);
    reduce_add<64><<<512, 256, 0, stream>>>(P, bgh, h4, g2);

    // pass 3: sB^T = (relu(g2) @ WB + bB)^T ; out = A@sB + cB
    gemm_rows<64, 16, 1, 0, 1><<<256, 256, 0, stream>>>(g2, WB, bB, StB);
    if (pre) agg_mfma<16, 0><<<dim3(128, 4), 256, 0, stream>>>(Abf, nullptr, nullptr, StB, P);
    else     agg_mfma<16, 2><<<dim3(128, 4), 256, 0, stream>>>(nullptr, adj, dis, StB, P);
    reduce_add<16><<<128, 256, 0, stream>>>(P, cB, nullptr, out);
}

// Round 5
// 370.088 us; speedup vs baseline: 5.3605x; 1.0368x over previous
//
#include <hip/hip_runtime.h>
#include <hip/hip_bf16.h>

#define NROWS 8192
typedef unsigned short u16;
typedef short bf16x8 __attribute__((ext_vector_type(8)));
typedef float f32x4 __attribute__((ext_vector_type(4)));

__device__ __forceinline__ u16 f2b(float f) {   // fp32 -> bf16 RNE (finite data)
    unsigned u = __float_as_uint(f);
    unsigned r = (u + 0x7fffu + ((u >> 16) & 1u)) >> 16;
    return (u16)r;
}

template<int MODE> __device__ __forceinline__ float actf(float v) {
    if constexpr (MODE == 1) return fmaxf(v, 0.f);
    else if constexpr (MODE == 2) return v > 0.f ? v : 0.2f * v;
    else return v;
}

// ---------------------------------------------------------------------------
// Weight folds, parallelized. ws layout (floats):
//   WA[128*64]@0  bA[64]@8192  cA[64]@8256  WB[64*16]@8320  bB[16]@9344
//   cB[16]@9360  T2[64*32]@9376  v1[128]@11424  v2[32]@11552  T1[128*128]@16384
// Shapes: W1[128,128] Wg1[128,128] Wm1[128,64] W2[64,32] Wg2[32,32] W3[32,16]
// ---------------------------------------------------------------------------
__global__ __launch_bounds__(256) void fold1(
    const float* __restrict__ W1, const float* __restrict__ b1,
    const float* __restrict__ Wg1,
    const float* __restrict__ W2, const float* __restrict__ b2,
    const float* __restrict__ Wg2, float* __restrict__ ws) {
    float* T2 = ws + 9376;
    float* v1 = ws + 11424;
    float* v2 = ws + 11552;
    float* T1 = ws + 16384;
    const int tid = threadIdx.x, b = blockIdx.x;
    if (b < 16) {                       // T1 = W1 @ Wg1 : rows [b*8, b*8+8)
        int i = b * 8 + (tid >> 5), j4 = (tid & 31) << 2;
        float4 acc = {0, 0, 0, 0};
        for (int k = 0; k < 128; ++k) {
            float a = W1[i * 128 + k];
            float4 g = *(const float4*)&Wg1[k * 128 + j4];
            acc.x += a * g.x; acc.y += a * g.y; acc.z += a * g.z; acc.w += a * g.w;
        }
        *(float4*)&T1[i * 128 + j4] = acc;
    } else if (b == 16) {               // v1 = b1 @ Wg1 ; v2 = b2 @ Wg2
        if (tid < 128) {
            float s = 0;
            for (int k = 0; k < 128; ++k) s += b1[k] * Wg1[k * 128 + tid];
            v1[tid] = s;
        } else if (tid < 160) {
            int j = tid - 128;
            float s = 0;
            for (int k = 0; k < 32; ++k) s += b2[k] * Wg2[k * 32 + j];
            v2[j] = s;
        }
    } else {                            // T2 = W2 @ Wg2
        for (int o4 = tid; o4 < 64 * 8; o4 += 256) {
            int i = o4 >> 3, j4 = (o4 & 7) << 2;
            float4 acc = {0, 0, 0, 0};
            for (int k = 0; k < 32; ++k) {
                float a = W2[i * 32 + k];
                float4 g = *(const float4*)&Wg2[k * 32 + j4];
                acc.x += a * g.x; acc.y += a * g.y; acc.z += a * g.z; acc.w += a * g.w;
            }
            *(float4*)&T2[i * 32 + j4] = acc;
        }
    }
}

__global__ __launch_bounds__(256) void fold2(
    const float* __restrict__ Wm1, const float* __restrict__ bm1,
    const float* __restrict__ bg1,
    const float* __restrict__ W3, const float* __restrict__ b3,
    const float* __restrict__ bg2, float* __restrict__ ws) {
    float* WA = ws + 0;
    float* bA = ws + 8192;
    float* cA = ws + 8256;
    float* WB = ws + 8320;
    float* bB = ws + 9344;
    float* cB = ws + 9360;
    const float* T2 = ws + 9376;
    const float* v1 = ws + 11424;
    const float* v2 = ws + 11552;
    const float* T1 = ws + 16384;
    const int tid = threadIdx.x, b = blockIdx.x;
    if (b < 8) {                        // WA = T1 @ Wm1 : rows [b*16, b*16+16)
        int i = b * 16 + (tid >> 4), j4 = (tid & 15) << 2;
        float4 acc = {0, 0, 0, 0};
        for (int k = 0; k < 128; ++k) {
            float a = T1[i * 128 + k];
            float4 g = *(const float4*)&Wm1[k * 64 + j4];
            acc.x += a * g.x; acc.y += a * g.y; acc.z += a * g.z; acc.w += a * g.w;
        }
        *(float4*)&WA[i * 64 + j4] = acc;
    } else if (b == 8) {                // bA,cA,bB,cB
        if (tid < 64) {
            float s = 0, c = 0;
            for (int k = 0; k < 128; ++k) {
                s += v1[k] * Wm1[k * 64 + tid];
                c += bg1[k] * Wm1[k * 64 + tid];
            }
            bA[tid] = s; cA[tid] = c + bm1[tid];
        } else if (tid < 80) {
            int j = tid - 64;
            float s = 0, c = 0;
            for (int k = 0; k < 32; ++k) {
                s += v2[k] * W3[k * 16 + j];
                c += bg2[k] * W3[k * 16 + j];
            }
            bB[j] = s; cB[j] = c + b3[j];
        }
    } else {                            // WB = T2 @ W3
        int i = tid >> 2, j4 = (tid & 3) << 2;
        float4 acc = {0, 0, 0, 0};
        for (int k = 0; k < 32; ++k) {
            float a = T2[i * 32 + k];
            float4 g = *(const float4*)&W3[k * 16 + j4];
            acc.x += a * g.x; acc.y += a * g.y; acc.z += a * g.z; acc.w += a * g.w;
        }
        *(float4*)&WB[i * 16 + j4] = acc;
    }
}

// ---------------------------------------------------------------------------
// Small row GEMM: out = AOUT( AIN(in)[N,K] @ W[K,M] + bias )
// OUTT=0: fp32 row-major [N,M].  OUTT=1: bf16 TRANSPOSED [M][NROWS] (S^T).
// ---------------------------------------------------------------------------
template<int K, int M, int AIN, int AOUT, int OUTT>
__global__ __launch_bounds__(256) void gemm_rows(
    const float* __restrict__ in, const float* __restrict__ W,
    const float* __restrict__ bias, void* __restrict__ outv) {
    constexpr int RB = 32;
    constexpr int TNs = (M >= 64) ? 4 : 2;
    constexpr int TXs = M / TNs;
    constexpr int TYs = 256 / TXs;
    constexpr int TMs = RB / TYs;
    static_assert(TMs >= 1 && TMs * TYs == RB, "bad cfg");
    __shared__ float in_t[K][RB + 4];
    __shared__ float w_s[K * M];
    __shared__ float bias_s[M];
    const int tid = threadIdx.x;
    const int b0 = blockIdx.x * RB;
    constexpr int K4 = K / 4;
    for (int g = tid; g < RB * K4; g += 256) {
        int r = g / K4, c4 = g % K4;
        float4 v = *(const float4*)&in[(size_t)(b0 + r) * K + c4 * 4];
        v.x = actf<AIN>(v.x); v.y = actf<AIN>(v.y);
        v.z = actf<AIN>(v.z); v.w = actf<AIN>(v.w);
        in_t[c4 * 4 + 0][r] = v.x;
        in_t[c4 * 4 + 1][r] = v.y;
        in_t[c4 * 4 + 2][r] = v.z;
        in_t[c4 * 4 + 3][r] = v.w;
    }
    for (int g = tid; g < K * M / 4; g += 256)
        ((float4*)w_s)[g] = ((const float4*)W)[g];
    if (tid < M) bias_s[tid] = bias ? bias[tid] : 0.f;
    __syncthreads();

    const int tx = tid % TXs, ty = tid / TXs;
    const int c0 = tx * TNs, r0 = ty * TMs;
    float acc[TMs][TNs] = {};
    for (int k = 0; k < K; ++k) {
        float a[TMs];
#pragma unroll
        for (int m = 0; m < TMs; ++m) a[m] = in_t[k][r0 + m];
        float w[TNs];
#pragma unroll
        for (int n = 0; n < TNs; ++n) w[n] = w_s[k * M + c0 + n];
#pragma unroll
        for (int m = 0; m < TMs; ++m)
#pragma unroll
            for (int n = 0; n < TNs; ++n) acc[m][n] += a[m] * w[n];
    }
#pragma unroll
    for (int m = 0; m < TMs; ++m) {
        float vres[TNs];
#pragma unroll
        for (int n = 0; n < TNs; ++n) vres[n] = actf<AOUT>(acc[m][n] + bias_s[c0 + n]);
        if constexpr (OUTT == 0) {
            float* op = &((float*)outv)[(size_t)(b0 + r0 + m) * M + c0];
            if constexpr (TNs == 4) { float4 o4 = {vres[0], vres[1], vres[2], vres[3]}; *(float4*)op = o4; }
            else                    { float2 o2 = {vres[0], vres[1]}; *(float2*)op = o2; }
        } else {
            u16* ot = (u16*)outv;
#pragma unroll
            for (int n = 0; n < TNs; ++n)
                ot[(size_t)(c0 + n) * NROWS + (b0 + r0 + m)] = f2b(vres[n]);
        }
    }
}

// ---------------------------------------------------------------------------
// MFMA aggregation: P[ky] = A[rows, kchunk] @ S   (bf16 MFMA, no LDS, no atomics)
// wave: 16 rows x F cols; A-frag/B-frag = direct 16B global loads.
// MODE 0: A from Abf (L3-warm).  MODE 1: A = bf16(adj*dis) on the fly
// (nontemporal reads), ALSO writes Abf (fused converter).  MODE 2: on the fly,
// no write (low-workspace fallback).
// ---------------------------------------------------------------------------
template<int F, int MODE, int KS>
__global__ __launch_bounds__(256) void agg_mfma(
    u16* __restrict__ Abf, const float* __restrict__ adj,
    const float* __restrict__ dis, const u16* __restrict__ St,
    float* __restrict__ Pout) {
    constexpr int CT = F / 16;
    constexpr int KCH = NROWS / KS;
    const int lane = threadIdx.x & 63;
    const int wid  = threadIdx.x >> 6;
    const int r0   = blockIdx.x * 64 + wid * 16;
    const int ky   = blockIdx.y;
    const int l15  = lane & 15;
    const int kb   = (lane >> 4) * 8;
    const int k0   = ky * KCH;
    f32x4 acc[CT] = {};
    size_t aoff = (size_t)(r0 + l15) * NROWS + k0 + kb;
    const u16* Bbase = St + (size_t)l15 * NROWS + k0 + kb;
#pragma unroll 4
    for (int ks = 0; ks < KCH; ks += 32) {
        bf16x8 af;
        if constexpr (MODE == 0) {
            af = *(const bf16x8*)(Abf + aoff);
        } else {
            const f32x4* a4 = (const f32x4*)(adj + aoff);
            const f32x4* d4 = (const f32x4*)(dis + aoff);
            f32x4 a0 = __builtin_nontemporal_load(a4);
            f32x4 a1 = __builtin_nontemporal_load(a4 + 1);
            f32x4 d0 = __builtin_nontemporal_load(d4);
            f32x4 d1 = __builtin_nontemporal_load(d4 + 1);
#pragma unroll
            for (int j = 0; j < 4; ++j) {
                af[j]     = (short)f2b(a0[j] * d0[j]);
                af[j + 4] = (short)f2b(a1[j] * d1[j]);
            }
            if constexpr (MODE == 1)
                *(bf16x8*)(Abf + aoff) = af;   // normal store -> lands in L2/L3
        }
#pragma unroll
        for (int ct = 0; ct < CT; ++ct) {
            bf16x8 bf = *(const bf16x8*)(Bbase + (size_t)ct * 16 * NROWS + ks);
            acc[ct] = __builtin_amdgcn_mfma_f32_16x16x32_bf16(af, bf, acc[ct], 0, 0, 0);
        }
        aoff += 32;
    }
    // C/D layout: col = lane&15, row = (lane>>4)*4 + i   [m89-verified]
    float* P = Pout + (size_t)ky * ((size_t)NROWS * F);
    const int rb = r0 + (lane >> 4) * 4;
#pragma unroll
    for (int ct = 0; ct < CT; ++ct)
#pragma unroll
        for (int i = 0; i < 4; ++i)
            P[(size_t)(rb + i) * F + ct * 16 + l15] = acc[ct][i];
}

// ---------------------------------------------------------------------------
// out = sum_{ky} P[ky] + bias[col] (+ res)
// ---------------------------------------------------------------------------
template<int F, int KS>
__global__ __launch_bounds__(256) void reduce_add(
    const float* __restrict__ P, const float* __restrict__ bias,
    const float* __restrict__ res, float* __restrict__ out) {
    constexpr int TOT4 = NROWS * F / 4;
    int i = blockIdx.x * 256 + threadIdx.x;
    if (i >= TOT4) return;
    constexpr size_t STR = (size_t)NROWS * F / 4;
    const float4* P4 = (const float4*)P;
    float4 s = P4[i];
#pragma unroll
    for (int k = 1; k < KS; ++k) {
        float4 t = P4[i + (size_t)k * STR];
        s.x += t.x; s.y += t.y; s.z += t.z; s.w += t.w;
    }
    float4 b = *(const float4*)&bias[(i % (F / 4)) * 4];
    s.x += b.x; s.y += b.y; s.z += b.z; s.w += b.w;
    if (res) {
        float4 r = ((const float4*)res)[i];
        s.x += r.x; s.y += r.y; s.z += r.z; s.w += r.w;
    }
    ((float4*)out)[i] = s;
}

extern "C" void kernel_launch(void* const* d_in, const int* in_sizes, int n_in,
                              void* d_out, int out_size, void* d_ws, size_t ws_size,
                              hipStream_t stream) {
    const float* x   = (const float*)d_in[0];
    const float* adj = (const float*)d_in[1];
    const float* dis = (const float*)d_in[2];
    const float* W1  = (const float*)d_in[3];
    const float* b1  = (const float*)d_in[4];
    const float* Wg1 = (const float*)d_in[5];
    const float* bg1 = (const float*)d_in[6];
    const float* Wm1 = (const float*)d_in[7];
    const float* bm1 = (const float*)d_in[8];
    const float* Wm2 = (const float*)d_in[9];
    const float* bm2 = (const float*)d_in[10];
    const float* Wm3 = (const float*)d_in[11];
    const float* bm3 = (const float*)d_in[12];
    const float* Wm4 = (const float*)d_in[13];
    const float* bm4 = (const float*)d_in[14];
    const float* Wgh = (const float*)d_in[15];
    const float* bgh = (const float*)d_in[16];
    const float* W2  = (const float*)d_in[17];
    const float* b2  = (const float*)d_in[18];
    const float* Wg2 = (const float*)d_in[19];
    const float* bg2 = (const float*)d_in[20];
    const float* W3  = (const float*)d_in[21];
    const float* b3  = (const float*)d_in[22];
    float* ws  = (float*)d_ws;
    float* out = (float*)d_out;

    constexpr int KS = 8;
    const size_t ABF_FLOATS = (size_t)NROWS * NROWS / 2;   // 128MB as floats
    // base floats: fold 40960 + St 262144 + P KS*524288 + gA/g2 524288 + h4 524288
    const size_t BASE_FLOATS = 40960 + 262144 + (size_t)KS * 524288 + 524288 + 524288;
    const size_t NEED_PRE_BYTES = (ABF_FLOATS + BASE_FLOATS) * 4ULL;  // ~156.4MB
    const bool pre = ws_size >= NEED_PRE_BYTES;

    float* base = ws + (pre ? ABF_FLOATS : 0);
    float* wsW  = base;                       // fold area: 40960 floats
    float* St_f = wsW + 40960;                // S^T bf16 [64][8192] (shared A/2/B)
    float* P    = St_f + 262144;              // partials: KS*8192*64
    float* h2   = P;                          // alias: P dead during med chain
    float* h3   = P + 1048576;                // alias
    float* gA   = P + (size_t)KS * 524288;    // [8192,64]
    float* h4   = gA + 524288;                // [8192,64]
    float* g2   = gA;                         // alias: gA dead after h2-gemm

    u16* Abf = (u16*)ws;
    u16* St  = (u16*)St_f;
    const float* WA = wsW + 0;
    const float* bA = wsW + 8192;
    const float* cA = wsW + 8256;
    const float* WB = wsW + 8320;
    const float* bB = wsW + 9344;
    const float* cB = wsW + 9360;

    fold1<<<18, 256, 0, stream>>>(W1, b1, Wg1, W2, b2, Wg2, wsW);
    fold2<<<10, 256, 0, stream>>>(Wm1, bm1, bg1, W3, b3, bg2, wsW);

    // pass 1 (fused converter): sA^T = (x @ WA + bA)^T ; gA = A@sA + cA
    gemm_rows<128, 64, 0, 0, 1><<<256, 256, 0, stream>>>(x, WA, bA, St);
    if (pre) agg_mfma<64, 1, KS><<<dim3(128, KS), 256, 0, stream>>>(Abf, adj, dis, St, P);
    else     agg_mfma<64, 2, KS><<<dim3(128, KS), 256, 0, stream>>>(nullptr, adj, dis, St, P);
    reduce_add<64, KS><<<512, 256, 0, stream>>>(P, cA, nullptr, gA);

    // med chain (h2,h3 alias into P — P is dead here)
    gemm_rows<64, 128, 2, 2, 0><<<256, 256, 0, stream>>>(gA, Wm2, bm2, h2);
    gemm_rows<128, 64, 0, 2, 0><<<256, 256, 0, stream>>>(h2, Wm3, bm3, h3);
    gemm_rows<64, 64, 0, 1, 0><<<256, 256, 0, stream>>>(h3, Wm4, bm4, h4);

    // pass 2: s2^T = (h4 @ Wgh)^T ; g2 = A@s2 + bgh + h4
    gemm_rows<64, 64, 0, 0, 1><<<256, 256, 0, stream>>>(h4, Wgh, nullptr, St);
    if (pre) agg_mfma<64, 0, KS><<<dim3(128, KS), 256, 0, stream>>>(Abf, nullptr, nullptr, St, P);
    else     agg_mfma<64, 2, KS><<<dim3(128, KS), 256, 0, stream>>>(nullptr, adj, dis, St, P);
    reduce_add<64, KS><<<512, 256, 0, stream>>>(P, bgh, h4, g2);

    // pass 3: sB^T = (relu(g2) @ WB + bB)^T ; out = A@sB + cB
    gemm_rows<64, 16, 1, 0, 1><<<256, 256, 0, stream>>>(g2, WB, bB, St);
    if (pre) agg_mfma<16, 0, KS><<<dim3(128, KS), 256, 0, stream>>>(Abf, nullptr, nullptr, St, P);
    else     agg_mfma<16, 2, KS><<<dim3(128, KS), 256, 0, stream>>>(nullptr, adj, dis, St, P);
    reduce_add<16, KS><<<128, 256, 0, stream>>>(P, cB, nullptr, out);
}